// Round 1
// baseline (8285.723 us; speedup 1.0000x reference)
//
#include <hip/hip_runtime.h>
#include <hip/hip_bf16.h>
#include <cstdint>

typedef __bf16 bf16;
typedef __bf16 bf16x8 __attribute__((ext_vector_type(8)));
typedef float  f32x4  __attribute__((ext_vector_type(4)));
typedef uint32_t u32x4 __attribute__((ext_vector_type(4)));

#define D_DIM   1024
#define ND      3072
#define B_SZ    32
#define U_SZ    512
#define T_SZ    513
#define M_REAL  (B_SZ * T_SZ)   // 16416
#define WXS_LD  1032            // padded k-stride (bf16 elems)
#define A_LD    1032
#define XP_LD   20              // xpx row stride (floats), 16B-aligned rows

#define AGENT __HIP_MEMORY_SCOPE_AGENT

__device__ __forceinline__ f32x4 mfma16(bf16x8 a, bf16x8 b, f32x4 c) {
    return __builtin_amdgcn_mfma_f32_16x16x32_bf16(a, b, c, 0, 0, 0);
}

struct bfpair { bf16x8 hi, lo; };

// split 8 consecutive fp32 into bf16 hi + bf16 residual lo
__device__ __forceinline__ bfpair split8(const float* p) {
    f32x4 a = *(const f32x4*)p;
    f32x4 b = *(const f32x4*)(p + 4);
    bfpair r;
#pragma unroll
    for (int j = 0; j < 4; ++j) {
        r.hi[j] = (bf16)a[j];
        r.lo[j] = (bf16)(a[j] - (float)r.hi[j]);
        r.hi[4 + j] = (bf16)b[j];
        r.lo[4 + j] = (bf16)(b[j] - (float)r.hi[4 + j]);
    }
    return r;
}

// convert 8 consecutive fp32 to bf16
__device__ __forceinline__ bf16x8 cvt8(const float* p) {
    f32x4 a = *(const f32x4*)p;
    f32x4 b = *(const f32x4*)(p + 4);
    bf16x8 r;
#pragma unroll
    for (int j = 0; j < 4; ++j) { r[j] = (bf16)a[j]; r[4 + j] = (bf16)b[j]; }
    return r;
}

// unpack 8 packed uint32 (hi bf16 | lo bf16 << 16) -> hi8, lo8 via v_perm
__device__ __forceinline__ bfpair unpack8(const uint32_t* p) {
    u32x4 a = *(const u32x4*)p;
    u32x4 b = *(const u32x4*)(p + 4);
    union { uint32_t u[4]; bf16x8 v; } H, L;
    H.u[0] = __builtin_amdgcn_perm(a.y, a.x, 0x05040100u);
    H.u[1] = __builtin_amdgcn_perm(a.w, a.z, 0x05040100u);
    H.u[2] = __builtin_amdgcn_perm(b.y, b.x, 0x05040100u);
    H.u[3] = __builtin_amdgcn_perm(b.w, b.z, 0x05040100u);
    L.u[0] = __builtin_amdgcn_perm(a.y, a.x, 0x07060302u);
    L.u[1] = __builtin_amdgcn_perm(a.w, a.z, 0x07060302u);
    L.u[2] = __builtin_amdgcn_perm(b.y, b.x, 0x07060302u);
    L.u[3] = __builtin_amdgcn_perm(b.w, b.z, 0x07060302u);
    bfpair r; r.hi = H.v; r.lo = L.v;
    return r;
}

// ---------------------------------------------------------------------------
// Transpose fp32 Wd [K][N] -> bf16 hi/lo planes WdT[N][K]
// ---------------------------------------------------------------------------
__global__ void transpose_split(const float* __restrict__ in,
                                bf16* __restrict__ out_hi, bf16* __restrict__ out_lo,
                                int R, int C) {
    __shared__ float tile[32][33];
    const int c0 = blockIdx.x * 32, r0 = blockIdx.y * 32;
    const int tx = threadIdx.x, ty = threadIdx.y;   // 32 x 8
    for (int i = 0; i < 32; i += 8)
        tile[ty + i][tx] = in[(size_t)(r0 + ty + i) * C + c0 + tx];
    __syncthreads();
    for (int i = 0; i < 32; i += 8) {
        const float v  = tile[tx][ty + i];
        const bf16  hi = (bf16)v;
        out_hi[(size_t)(c0 + ty + i) * R + r0 + tx] = hi;
        out_lo[(size_t)(c0 + ty + i) * R + r0 + tx] = (bf16)(v - (float)hi);
    }
}

// ---------------------------------------------------------------------------
// GRU scan, restructured (R7):
//   64 blocks x 256 threads; block = one 16-col n-slice, all 32 batches.
//   Waves 0/1 = gate waves (batches 0-15 / 16-31): swapped-operand MFMA
//     (A = Wh fragment in registers, all 3 gates; B = h fragment) so each
//     lane holds 4 consecutive n x 1 batch x {z,r,h} -> gates fully
//     in-register, no hp LDS round trip. Publication = 2x u64 atomic
//     exchange per lane (4 packed words, consecutive n).
//   Waves 2/3 = xp(t+1) producers (double-buffered xpx), free-running.
//   ONE __syncthreads per step; barrier = one-hop: every gate lane polls
//   one of 64 slot flags directly (no leader / go line).
// ---------------------------------------------------------------------------
__global__ __launch_bounds__(256, 1)
void gru_scan(const float* __restrict__ Wx,    const float* __restrict__ Wh,
              const float* __restrict__ bx,    const float* __restrict__ bh,
              const float* __restrict__ h0,    const float* __restrict__ embed,
              const int* __restrict__ y,       uint32_t* __restrict__ ghs,
              int* __restrict__ flags)
{
    __shared__ __align__(16) bf16 WxS[48 * WXS_LD];       // [c = gate*16+cl][k]
    __shared__ __align__(16) float xpx[2][96 * XP_LD];    // [g*32+batch][n-sub]
    __shared__ __align__(16) float bxs[3][16], bhs[3][16];

    const int tid  = threadIdx.x;
    const int wave = tid >> 6, lane = tid & 63;
    const int quad = lane >> 4, l15 = lane & 15;
    const int n0 = blockIdx.x * 16;
    int* slots = flags;          // slot for block b at flags[b*16]  (64-B stride)

    // ---- one-time: gather Wx slice [48 cols][1024 k] from fp32 Wx[k][3D] ----
    for (int idx = tid; idx < 3 * 1024 * 16; idx += 256) {
        const int cl = idx & 15;
        const int k  = (idx >> 4) & 1023;
        const int g  = idx >> 14;            // 0..2
        WxS[(g * 16 + cl) * WXS_LD + k] = (bf16)Wx[(size_t)k * ND + g * D_DIM + n0 + cl];
    }
    if (tid < 48) {
        bxs[tid >> 4][tid & 15] = bx[(tid >> 4) * D_DIM + n0 + (tid & 15)];
        bhs[tid >> 4][tid & 15] = bh[(tid >> 4) * D_DIM + n0 + (tid & 15)];
    }

    // ---- one-time: Wh slice for ALL 3 gates into gate-wave registers ----
    // A-fragment: lane supplies Wh[k = ks*32+quad*8+j][n0+l15]
    bf16x8 bregZ[32], bregR[32], bregH[32];
    if (wave < 2) {
#pragma unroll
        for (int ks = 0; ks < 32; ++ks) {
            bf16x8 vz, vr, vh;
#pragma unroll
            for (int j = 0; j < 8; ++j) {
                const size_t krow = (size_t)(ks * 32 + quad * 8 + j) * ND + n0 + l15;
                vz[j] = (bf16)Wh[krow];
                vr[j] = (bf16)Wh[krow + D_DIM];
                vh[j] = (bf16)Wh[krow + 2 * D_DIM];
            }
            bregZ[ks] = vz; bregR[ks] = vr; bregH[ks] = vh;
        }
    }

    // gate waves: batch = (wave&1)*16 + l15, n = n0 + quad*4 + i
    // xp waves (2,3): same batch formula covers 0..31
    const int batch = (wave & 1) * 16 + l15;
    f32x4 holdv = *(const f32x4*)(h0 + n0 + quad * 4);   // h0 broadcast over batch
    unsigned long long junk = 0;

    __syncthreads();   // WxS / biases ready

    // ---- pre-loop: xp(0), all tokens NULL (embed row 0) -> xpx[0] ----
    if (wave >= 2) {
        const float* xrow = embed + quad * 8;
        f32x4 ax0 = {}, ax1 = {}, ax2 = {};
#pragma unroll
        for (int ks = 0; ks < 32; ++ks) {
            bf16x8 xa = cvt8(xrow + ks * 32);
            bf16x8 w0 = *(const bf16x8*)(WxS + (l15)      * WXS_LD + ks * 32 + quad * 8);
            bf16x8 w1 = *(const bf16x8*)(WxS + (16 + l15) * WXS_LD + ks * 32 + quad * 8);
            bf16x8 w2 = *(const bf16x8*)(WxS + (32 + l15) * WXS_LD + ks * 32 + quad * 8);
            ax0 = mfma16(w0, xa, ax0);   // rows = n-sub, cols = batch
            ax1 = mfma16(w1, xa, ax1);
            ax2 = mfma16(w2, xa, ax2);
        }
        *(f32x4*)(xpx[0] + (batch)      * XP_LD + quad * 4) = ax0;
        *(f32x4*)(xpx[0] + (32 + batch) * XP_LD + quad * 4) = ax1;
        *(f32x4*)(xpx[0] + (64 + batch) * XP_LD + quad * 4) = ax2;
    }
    __syncthreads();   // xpx[0] ready

    for (int t = 0; t < T_SZ; ++t) {
        if (wave < 2) {
            // ---- hp = Wh^T-slice * h_{t-1}: 6 chains (3 gates x hi/lo h) ----
            f32x4 azh = {}, azl = {}, arh = {}, arl = {}, ahh = {}, ahl = {};
            if (t == 0) {
                const float* hrow = h0 + quad * 8;
#pragma unroll
                for (int ks = 0; ks < 32; ++ks) {
                    bfpair h8 = split8(hrow + ks * 32);
                    azh = mfma16(bregZ[ks], h8.hi, azh);
                    azl = mfma16(bregZ[ks], h8.lo, azl);
                    arh = mfma16(bregR[ks], h8.hi, arh);
                    arl = mfma16(bregR[ks], h8.lo, arl);
                    ahh = mfma16(bregH[ks], h8.hi, ahh);
                    ahl = mfma16(bregH[ks], h8.lo, ahl);
                }
            } else {
                const uint32_t* hrow = ghs
                    + ((size_t)batch * T_SZ + (t - 1)) * D_DIM + quad * 8;
#pragma unroll
                for (int ks = 0; ks < 32; ++ks) {
                    bfpair h8 = unpack8(hrow + ks * 32);
                    azh = mfma16(bregZ[ks], h8.hi, azh);
                    azl = mfma16(bregZ[ks], h8.lo, azl);
                    arh = mfma16(bregR[ks], h8.hi, arh);
                    arl = mfma16(bregR[ks], h8.lo, arl);
                    ahh = mfma16(bregH[ks], h8.hi, ahh);
                    ahl = mfma16(bregH[ks], h8.lo, ahl);
                }
            }

            // ---- gates fully in-register: 4 n-values x 1 batch per lane ----
            const int p = t & 1;
            const f32x4 xz = *(const f32x4*)(xpx[p] + (batch)      * XP_LD + quad * 4);
            const f32x4 xr = *(const f32x4*)(xpx[p] + (32 + batch) * XP_LD + quad * 4);
            const f32x4 xh = *(const f32x4*)(xpx[p] + (64 + batch) * XP_LD + quad * 4);
            const f32x4 bxz = *(const f32x4*)(&bxs[0][quad * 4]);
            const f32x4 bxr = *(const f32x4*)(&bxs[1][quad * 4]);
            const f32x4 bxh = *(const f32x4*)(&bxs[2][quad * 4]);
            const f32x4 bhz = *(const f32x4*)(&bhs[0][quad * 4]);
            const f32x4 bhr = *(const f32x4*)(&bhs[1][quad * 4]);
            const f32x4 bhh = *(const f32x4*)(&bhs[2][quad * 4]);
            uint32_t pk[4];
#pragma unroll
            for (int i = 0; i < 4; ++i) {
                const float hz  = azh[i] + azl[i] + bhz[i];
                const float hr  = arh[i] + arl[i] + bhr[i];
                const float hhv = ahh[i] + ahl[i] + bhh[i];
                const float z  = 1.f / (1.f + __expf(-(xz[i] + bxz[i] + hz)));
                const float r  = 1.f / (1.f + __expf(-(xr[i] + bxr[i] + hr)));
                const float pa = xh[i] + bxh[i] + r * hhv;
                const float hc = 1.f - 2.f / (__expf(2.f * pa) + 1.f);   // tanh(pa)
                const float hn = z * holdv[i] + (1.f - z) * hc;
                holdv[i] = hn;
                const bf16 hi = (bf16)hn;
                const bf16 lo = (bf16)(hn - (float)hi);
                pk[i] = (uint32_t)__builtin_bit_cast(uint16_t, hi)
                      | ((uint32_t)__builtin_bit_cast(uint16_t, lo) << 16);
            }
            // ---- publish: two u64 returning exchanges (4 consecutive n) ----
            const unsigned long long e0 = (unsigned long long)pk[0]
                                        | ((unsigned long long)pk[1] << 32);
            const unsigned long long e1 = (unsigned long long)pk[2]
                                        | ((unsigned long long)pk[3] << 32);
            unsigned long long* dst = (unsigned long long*)
                (ghs + ((size_t)batch * T_SZ + t) * D_DIM + n0 + quad * 4);
            junk ^= __hip_atomic_exchange(dst,     e0, __ATOMIC_RELAXED, AGENT);
            junk ^= __hip_atomic_exchange(dst + 1, e1, __ATOMIC_RELAXED, AGENT);
        } else if (t < U_SZ) {
            // ---- xp(t+1), off critical path ----
            const int tok = y[batch * U_SZ + t] & 1023;   // token at step t+1
            const float* xrow = embed + (size_t)tok * D_DIM + quad * 8;
            const int p = (t + 1) & 1;
            f32x4 ax0 = {}, ax1 = {}, ax2 = {};
#pragma unroll
            for (int ks = 0; ks < 32; ++ks) {
                bf16x8 xa = cvt8(xrow + ks * 32);
                bf16x8 w0 = *(const bf16x8*)(WxS + (l15)      * WXS_LD + ks * 32 + quad * 8);
                bf16x8 w1 = *(const bf16x8*)(WxS + (16 + l15) * WXS_LD + ks * 32 + quad * 8);
                bf16x8 w2 = *(const bf16x8*)(WxS + (32 + l15) * WXS_LD + ks * 32 + quad * 8);
                ax0 = mfma16(w0, xa, ax0);
                ax1 = mfma16(w1, xa, ax1);
                ax2 = mfma16(w2, xa, ax2);
            }
            *(f32x4*)(xpx[p] + (batch)      * XP_LD + quad * 4) = ax0;
            *(f32x4*)(xpx[p] + (32 + batch) * XP_LD + quad * 4) = ax1;
            *(f32x4*)(xpx[p] + (64 + batch) * XP_LD + quad * 4) = ax2;
        }

        // Single per-step barrier: drains exchanges (vmcnt0) + orders xpx.
        __syncthreads();

        // ---- one-hop device barrier: direct peer polling of 64 slots ----
        if (t + 1 < T_SZ) {
            const int tv = t + 1;
            if (tid == 0)
                __hip_atomic_store(slots + (blockIdx.x << 4), tv,
                                   __ATOMIC_RELAXED, AGENT);
            if (wave < 2) {
                int s;
                do {
                    s = __hip_atomic_load(slots + (lane << 4),
                                          __ATOMIC_RELAXED, AGENT);
                } while (__any(s < tv));
            }
            // xp waves free-run: their next-step xpx slot is disjoint, and
            // they touch no cross-block state.
        }
    }

    // consume junk so the exchanges keep their returning form
    if (junk == 0xDEADBEEFDEADBEEFull) flags[1023] = 1;
}

// ---------------------------------------------------------------------------
// In-place row-block GEMM: rows (packed hi/lo h) -> fp32 out rows.
// ---------------------------------------------------------------------------
__global__ __launch_bounds__(256, 1)
void gemm_rows_inplace(float* __restrict__ C,
                       const bf16* __restrict__ WdTh, const bf16* __restrict__ WdTl,
                       const float* __restrict__ bd)
{
    __shared__ __align__(16) bf16 Ah[32 * A_LD];
    __shared__ __align__(16) bf16 Al[32 * A_LD];
    const int tid  = threadIdx.x;
    const int wave = tid >> 6, lane = tid & 63;
    const int quad = lane >> 4, l15 = lane & 15;
    const size_t r0 = (size_t)blockIdx.x * 32;
    const uint32_t* Cw = (const uint32_t*)C;

    for (int idx = tid; idx < 32 * 128; idx += 256) {
        const int r = idx >> 7, ch = idx & 127;
        bfpair p = unpack8(Cw + (r0 + r) * D_DIM + ch * 8);
        *(bf16x8*)(Ah + r * A_LD + ch * 8) = p.hi;
        *(bf16x8*)(Al + r * A_LD + ch * 8) = p.lo;
    }
    __syncthreads();

    f32x4 acc[2][16] = {};
    const int nbase = wave * 256;
    for (int ks = 0; ks < 32; ++ks) {
        bf16x8 a0h = *(const bf16x8*)(Ah + (l15)      * A_LD + ks * 32 + quad * 8);
        bf16x8 a0l = *(const bf16x8*)(Al + (l15)      * A_LD + ks * 32 + quad * 8);
        bf16x8 a1h = *(const bf16x8*)(Ah + (16 + l15) * A_LD + ks * 32 + quad * 8);
        bf16x8 a1l = *(const bf16x8*)(Al + (16 + l15) * A_LD + ks * 32 + quad * 8);
#pragma unroll
        for (int nt = 0; nt < 16; ++nt) {
            const size_t boff = (size_t)(nbase + nt * 16 + l15) * D_DIM + ks * 32 + quad * 8;
            bf16x8 bhv = *(const bf16x8*)(WdTh + boff);
            bf16x8 blv = *(const bf16x8*)(WdTl + boff);
            acc[0][nt] = mfma16(a0h, bhv, acc[0][nt]);
            acc[0][nt] = mfma16(a0l, bhv, acc[0][nt]);
            acc[0][nt] = mfma16(a0h, blv, acc[0][nt]);
            acc[1][nt] = mfma16(a1h, bhv, acc[1][nt]);
            acc[1][nt] = mfma16(a1l, bhv, acc[1][nt]);
            acc[1][nt] = mfma16(a1h, blv, acc[1][nt]);
        }
    }

#pragma unroll
    for (int nt = 0; nt < 16; ++nt) {
        const int col = nbase + nt * 16 + l15;
        const float bvl = bd[col];
#pragma unroll
        for (int mt = 0; mt < 2; ++mt)
#pragma unroll
            for (int i = 0; i < 4; ++i)
                C[(r0 + mt * 16 + quad * 4 + i) * D_DIM + col] =
                    acc[mt][nt][i] + bvl;
    }
}

// ---------------------------------------------------------------------------
extern "C" void kernel_launch(void* const* d_in, const int* in_sizes, int n_in,
                              void* d_out, int out_size, void* d_ws, size_t ws_size,
                              hipStream_t stream) {
    (void)in_sizes; (void)n_in; (void)out_size; (void)ws_size;
    const int*   y     = (const int*)  d_in[0];
    const float* embed = (const float*)d_in[1];
    const float* Wx    = (const float*)d_in[2];
    const float* Wh    = (const float*)d_in[3];
    const float* bx    = (const float*)d_in[4];
    const float* bh    = (const float*)d_in[5];
    const float* Wd    = (const float*)d_in[6];
    const float* bd    = (const float*)d_in[7];
    const float* h0    = (const float*)d_in[8];
    float* out = (float*)d_out;

    // workspace: WdT hi/lo (2+2 MB) + flags (8 KB)
    bf16* WdTh = (bf16*)d_ws;
    bf16* WdTl = WdTh + (size_t)D_DIM * D_DIM;
    int* flags = (int*)((char*)d_ws + (size_t)D_DIM * D_DIM * 4);

    hipMemsetAsync(flags, 0, 8192, stream);

    transpose_split<<<dim3(D_DIM / 32, D_DIM / 32), dim3(32, 8), 0, stream>>>(
        Wd, WdTh, WdTl, D_DIM, D_DIM);

    // GRU scan with fused input projections; packed h history -> d_out rows
    gru_scan<<<64, 256, 0, stream>>>(Wx, Wh, bx, bh, h0, embed, y,
                                     (uint32_t*)out, flags);

    // In-place: out rows = h rows @ Wd + bd
    gemm_rows_inplace<<<M_REAL / 32, 256, 0, stream>>>(out, WdTh, WdTl, bd);
}